// Round 1
// baseline (535.767 us; speedup 1.0000x reference)
//
#include <hip/hip_runtime.h>

// GaussianBlur2D: separable 201-tap Gaussian (sigma=25, zero-padded), fp32.
// T=64, H=544, W=960. Two passes:
//   pass1 (vertical, H-axis)  -> d_out
//   pass2 (horizontal, W-axis) in-place on d_out (row-local blocks, safe).
// Compute-bound on fp32 VALU: 13.44e9 FMA total -> ~171us floor at 157 TF.

#define HH   544
#define WWD  960
#define PADC 100
#define KSIZE 201
#define RV   16     // h-rows per thread in pass1

// ---- compile-time Gaussian table (double Taylor exp, rounded to f32) ----
constexpr double cexp_taylor(double x) {   // x in [-8, 0]
  double term = 1.0, sum = 1.0;
  for (int n = 1; n < 120; ++n) { term *= x / n; sum += term; }
  return sum;
}
struct KTab { float v[KSIZE + 7]; };
constexpr KTab make_kt() {
  KTab t{};
  for (int i = 0; i < KSIZE; ++i) {
    double r = (double)(i - PADC);
    double x = -(r * r) / (2.0 * 25.0 * 25.0);
    t.v[i] = (float)(cexp_taylor(x) / (25.0 * 2.5066282746310002)); // /(sigma*sqrt(2pi))
  }
  for (int i = KSIZE; i < KSIZE + 7; ++i) t.v[i] = 0.0f;
  return t;
}
__device__ __constant__ KTab KT = make_kt();

// ---------------- pass 1: vertical conv along H ----------------
// block 256 threads; thread owns columns (w, w+1) and RV=16 consecutive h.
// input-major sliding window: per input row, 1 float2 load + 16x2 FMAs with
// wave-uniform k (scalar loads). grid = (2, H/RV=34, T=64).
__global__ __launch_bounds__(256) void vpass(const float* __restrict__ x,
                                             float* __restrict__ y) {
  const int tid = threadIdx.x;
  const int w   = 2 * (blockIdx.x * 256 + tid);
  const int h0  = blockIdx.y * RV;
  const int t   = blockIdx.z;
  if (w >= WWD) return;

  const float* xp = x + (size_t)t * HH * WWD + w;

  float ax[RV], ay[RV];
#pragma unroll
  for (int r = 0; r < RV; ++r) { ax[r] = 0.f; ay[r] = 0.f; }

  // input row j = h0 + b contributes to output r when 0 <= b+PAD-r <= 200
  const int blo = (h0 < PADC) ? -h0 : -PADC;                    // j >= 0
  const int bhi_all = RV - 1 + PADC;
  const int bhi = (h0 + bhi_all > HH - 1) ? (HH - 1 - h0) : bhi_all; // j < H

  // head: b in [blo, -86], only r <= b+PAD valid
  {
    const int bh = (bhi < -(PADC - RV + 1)) ? bhi : -(PADC - RV + 1); // -86
    for (int b = blo; b <= bh; ++b) {
      const float2 v = *(const float2*)(xp + (size_t)(h0 + b) * WWD);
#pragma unroll
      for (int r = 0; r < RV; ++r)
        if (r <= b + PADC) {
          const float kk = KT.v[b + PADC - r];
          ax[r] = fmaf(kk, v.x, ax[r]);
          ay[r] = fmaf(kk, v.y, ay[r]);
        }
    }
  }
  // interior: b in [-85, 100], all 16 r valid
  {
    const int bi = (blo > -(PADC - RV + 1) + 1) ? blo : -(PADC - RV + 1) + 1; // -85
    const int bt = (bhi < PADC) ? bhi : PADC;                                 // 100
#pragma unroll 4
    for (int b = bi; b <= bt; ++b) {
      const float2 v = *(const float2*)(xp + (size_t)(h0 + b) * WWD);
#pragma unroll
      for (int r = 0; r < RV; ++r) {
        const float kk = KT.v[b + PADC - r];
        ax[r] = fmaf(kk, v.x, ax[r]);
        ay[r] = fmaf(kk, v.y, ay[r]);
      }
    }
  }
  // tail: b in [101, bhi], only r >= b-PAD valid
  for (int b = PADC + 1; b <= bhi; ++b) {
    const float2 v = *(const float2*)(xp + (size_t)(h0 + b) * WWD);
#pragma unroll
    for (int r = 0; r < RV; ++r)
      if (r >= b - PADC) {
        const float kk = KT.v[b + PADC - r];
        ax[r] = fmaf(kk, v.x, ax[r]);
        ay[r] = fmaf(kk, v.y, ay[r]);
      }
  }

  float* yp = y + (size_t)t * HH * WWD + (size_t)h0 * WWD + w;
#pragma unroll
  for (int r = 0; r < RV; ++r) {
    float2 o; o.x = ax[r]; o.y = ay[r];
    *(float2*)(yp + (size_t)r * WWD) = o;
  }
}

// ---------------- pass 2: horizontal conv along W, in-place ----------------
// one block per (t,h) row. Stage row + zero pads into LDS; thread owns 4
// consecutive w; window read as conflict-free ds_read_b128 float4 chunks.
// i = 4m + e - r, m in [0,50]; m=0 needs e>=r, m=50 needs e<=r.
__global__ __launch_bounds__(256) void hpass(float* __restrict__ y) {
  __shared__ __align__(16) float row[1160]; // words: x-word + 100, x-word in [-100,1059]
  const int tid = threadIdx.x;
  float* yp = y + (size_t)blockIdx.x * WWD;

  // zero pads: words [0,100) and [1060,1160)
  if (tid < 25) {
    float4 z; z.x = z.y = z.z = z.w = 0.f;
    *(float4*)&row[4 * tid] = z;
  } else if (tid >= 32 && tid < 57) {
    float4 z; z.x = z.y = z.z = z.w = 0.f;
    *(float4*)&row[1060 + 4 * (tid - 32)] = z;
  }
  if (tid < 240)
    *(float4*)&row[100 + 4 * tid] = *(const float4*)(yp + 4 * tid);
  __syncthreads();

  if (tid < 240) {
    float acc[4] = {0.f, 0.f, 0.f, 0.f};

    { // m = 0 peel: valid when e >= r
      float4 q = *(const float4*)&row[4 * tid];
      const float* qf = (const float*)&q;
#pragma unroll
      for (int e = 0; e < 4; ++e)
#pragma unroll
        for (int r = 0; r < 4; ++r)
          if (e >= r) acc[r] = fmaf(KT.v[e - r], qf[e], acc[r]);
    }
    // interior m = 1..49: all 16 (e,r) valid
#pragma unroll 7
    for (int m = 1; m < 50; ++m) {
      float4 q = *(const float4*)&row[4 * (tid + m)];
      const float* qf = (const float*)&q;
#pragma unroll
      for (int e = 0; e < 4; ++e) {
        const float xv = qf[e];
#pragma unroll
        for (int r = 0; r < 4; ++r)
          acc[r] = fmaf(KT.v[4 * m + e - r], xv, acc[r]);
      }
    }
    { // m = 50 peel: valid when e <= r
      float4 q = *(const float4*)&row[4 * (tid + 50)];
      const float* qf = (const float*)&q;
#pragma unroll
      for (int e = 0; e < 4; ++e)
#pragma unroll
        for (int r = 0; r < 4; ++r)
          if (e <= r) acc[r] = fmaf(KT.v[200 + e - r], qf[e], acc[r]);
    }

    float4 o; o.x = acc[0]; o.y = acc[1]; o.z = acc[2]; o.w = acc[3];
    *(float4*)(yp + 4 * tid) = o;
  }
}

extern "C" void kernel_launch(void* const* d_in, const int* in_sizes, int n_in,
                              void* d_out, int out_size, void* d_ws, size_t ws_size,
                              hipStream_t stream) {
  const float* x = (const float*)d_in[0];
  float* out = (float*)d_out;
  (void)d_ws; (void)ws_size; (void)in_sizes; (void)n_in; (void)out_size;

  dim3 blk(256);
  dim3 g1(2, HH / RV, 64);      // (w-tiles of 512, 34 h-chunks, 64 frames)
  vpass<<<g1, blk, 0, stream>>>(x, out);

  dim3 g2(64 * HH);             // one block per (t,h) row
  hpass<<<g2, blk, 0, stream>>>(out);
}

// Round 2
// 530.953 us; speedup vs baseline: 1.0091x; 1.0091x over previous
//
#include <hip/hip_runtime.h>

// GaussianBlur2D: separable 201-tap Gaussian (sigma=25, zero-pad), fp32.
// T=64, H=544, W=960.
//   vpass: vertical, RV=32 rows/thread, XCD frame swizzle (frame=2.09MB < 4MiB L2)
//   hpass: horizontal in-place, LDS row stage, 8 out/thread, literal taps.
// fp32-VALU floor ~171us total (13.4e9 FMA at 157 TF).

#define HH   544
#define WWD  960
#define PADC 100
#define RV   32

// ---- compile-time Gaussian (double Taylor exp, rounded to f32) ----
constexpr double cexp_taylor(double x) {
  double term = 1.0, sum = 1.0;
  for (int n = 1; n < 120; ++n) { term *= x / n; sum += term; }
  return sum;
}
constexpr float gaussk(int k) {            // tap k in [0,200], else 0
  if (k < 0 || k > 200) return 0.0f;
  double r = (double)(k - PADC);
  return (float)(cexp_taylor(-(r * r) / (2.0 * 25.0 * 25.0))
                 / (25.0 * 2.5066282746310002));
}
// vpass table: runtime-indexed, zero-padded. idx = b + 131 - r, b in [-100,131],
// r in [0,32) -> idx in [0,262]. Value = K[b+100-r] or 0.
struct KTabZ { float v[272]; };
constexpr KTabZ make_ktz() {
  KTabZ t{};
  for (int i = 0; i < 272; ++i) t.v[i] = gaussk(i - 31);
  return t;
}
__device__ __constant__ KTabZ KTZ = make_ktz();

// hpass table: compile-time-indexed after full unroll -> inline literals.
// idx = 4j + e - r + 8 in [1,215]; value = K[idx-8] or 0.
struct KTabE { float v[216]; };
constexpr KTabE make_kte() {
  KTabE t{};
  for (int i = 0; i < 216; ++i) t.v[i] = gaussk(i - 8);
  return t;
}
constexpr KTabE KTE = make_kte();

// ---------------- pass 1: vertical conv along H ----------------
// 1D grid of 2176 blocks, decoded so frame t lands on XCD t%8 (lid%8 round
// robin assumption; perf heuristic only). Block = (w-tile of 512, h-chunk of
// 32, frame). Thread owns 2 columns x 32 rows; input-major sliding window:
// per input row 1 float2 load + 64 FMA with wave-uniform zero-padded taps.
__global__ __launch_bounds__(256) void vpass(const float* __restrict__ x,
                                             float* __restrict__ y) {
  const int lid = blockIdx.x;          // 0..2175
  const int xcd = lid & 7;
  const int s   = lid >> 3;            // 0..271
  const int f   = s / 34;              // 0..7
  const int r34 = s - 34 * f;          // 0..33
  const int t   = (f << 3) | xcd;      // frame
  const int wt  = r34 & 1;
  const int hc  = r34 >> 1;            // 0..16
  const int tid = threadIdx.x;
  const int w   = 2 * (wt * 256 + tid);
  const int h0  = hc * RV;
  if (w >= WWD) return;

  const float* xp = x + (size_t)t * (HH * WWD) + w;

  float ax[RV], ay[RV];
#pragma unroll
  for (int r = 0; r < RV; ++r) { ax[r] = 0.f; ay[r] = 0.f; }

  const int blo = (h0 < PADC) ? -h0 : -PADC;
  const int bmax = RV - 1 + PADC;                                 // 131
  const int bhi = (h0 + bmax > HH - 1) ? (HH - 1 - h0) : bmax;

  for (int b = blo; b <= bhi; ++b) {
    const float2 v = *(const float2*)(xp + (size_t)(h0 + b) * WWD);
    const float* kb = &KTZ.v[b + 131];
#pragma unroll
    for (int r = 0; r < RV; ++r) {
      const float kk = kb[-r];         // uniform scalar load, 0 when invalid
      ax[r] = fmaf(kk, v.x, ax[r]);
      ay[r] = fmaf(kk, v.y, ay[r]);
    }
  }

  float* yp = y + (size_t)t * (HH * WWD) + (size_t)h0 * WWD + w;
#pragma unroll
  for (int r = 0; r < RV; ++r) {
    float2 o; o.x = ax[r]; o.y = ay[r];
    *(float2*)(yp + (size_t)r * WWD) = o;
  }
}

// ---------------- pass 2: horizontal conv along W, in-place ----------------
// Block = 256 threads = 2 rows; half-block (lt in [0,120)) owns one row.
// Row staged in LDS as 290 16B blocks (25 zero + 240 data + 25 zero), XOR
// swizzled (q ^ (q>>3)&1) so the stride-2-block read pattern hits all 8 bank
// quads. Thread computes 8 consecutive w; 52 b128 reads, 1664 literal-tap FMA.
__device__ __forceinline__ int swz(int q) { return q ^ ((q >> 3) & 1); }

__global__ __launch_bounds__(256) void hpass(float* __restrict__ y) {
  __shared__ __align__(16) float4 row[2][292];
  const int tid = threadIdx.x;
  const int hh  = tid >> 7;            // which row of the pair
  const int lt  = tid & 127;
  float* yp = y + (size_t)(blockIdx.x * 2 + hh) * WWD;

  const float4 z4 = {0.f, 0.f, 0.f, 0.f};
  if (lt < 25) {
    row[hh][swz(lt)] = z4;                         // blocks [0,25): left pad
  } else if (lt >= 32 && lt < 57) {
    row[hh][swz(265 + lt - 32)] = z4;              // blocks [265,290): right pad
  }
  if (lt < 120) {
    const int q0 = 25 + 2 * lt;                    // data blocks [25,265)
    row[hh][swz(q0)]     = *(const float4*)(yp + 8 * lt);
    row[hh][swz(q0 + 1)] = *(const float4*)(yp + 8 * lt + 4);
  }
  __syncthreads();

  if (lt < 120) {
    float acc[8] = {0.f, 0.f, 0.f, 0.f, 0.f, 0.f, 0.f, 0.f};
#pragma unroll
    for (int j = 0; j < 52; ++j) {
      const int q = 2 * lt + j;
      const float4 v = row[hh][swz(q)];
      const float* vf = (const float*)&v;
#pragma unroll
      for (int e = 0; e < 4; ++e) {
        const float xv = vf[e];
#pragma unroll
        for (int r = 0; r < 8; ++r)
          acc[r] = fmaf(KTE.v[4 * j + e - r + 8], xv, acc[r]);
      }
    }
    float4 o0; o0.x = acc[0]; o0.y = acc[1]; o0.z = acc[2]; o0.w = acc[3];
    float4 o1; o1.x = acc[4]; o1.y = acc[5]; o1.z = acc[6]; o1.w = acc[7];
    *(float4*)(yp + 8 * lt)     = o0;
    *(float4*)(yp + 8 * lt + 4) = o1;
  }
}

extern "C" void kernel_launch(void* const* d_in, const int* in_sizes, int n_in,
                              void* d_out, int out_size, void* d_ws, size_t ws_size,
                              hipStream_t stream) {
  const float* x = (const float*)d_in[0];
  float* out = (float*)d_out;
  (void)d_ws; (void)ws_size; (void)in_sizes; (void)n_in; (void)out_size;

  vpass<<<dim3(2 * (HH / RV) * 64), dim3(256), 0, stream>>>(x, out);
  hpass<<<dim3(64 * HH / 2), dim3(256), 0, stream>>>(out);
}

// Round 3
// 472.467 us; speedup vs baseline: 1.1340x; 1.1238x over previous
//
#include <hip/hip_runtime.h>

// GaussianBlur2D: separable 201-tap Gaussian (sigma=25, zero-pad), fp32.
// T=64, H=544, W=960.
//   vpass: vertical, 32 rows/thread, fixed-trip masked loop (unroll 8),
//          __launch_bounds__(256,4) so 64 accumulators stay in VGPRs.
//   hpass: horizontal in-place, LDS float4 sliding window, 8 out/thread.
// fp32-VALU floor ~171us total (13.4e9 FMA at 157 TF; no fp32 MFMA on CDNA4).

#define HH   544
#define WWD  960
#define PADC 100
#define RV   32

// ---- compile-time Gaussian (double Taylor exp, rounded to f32) ----
constexpr double cexp_taylor(double x) {
  double term = 1.0, sum = 1.0;
  for (int n = 1; n < 120; ++n) { term *= x / n; sum += term; }
  return sum;
}
constexpr float gaussk(int k) {            // tap k in [0,200], else 0
  if (k < 0 || k > 200) return 0.0f;
  double r = (double)(k - PADC);
  return (float)(cexp_taylor(-(r * r) / (2.0 * 25.0 * 25.0))
                 / (25.0 * 2.5066282746310002));
}
// vpass table: tap for (bb, r) = gaussk(bb - r) = KTZ.v[bb + 31 - r],
// bb in [0,232), r in [0,32) -> idx in [0,262]. Zero-padded.
struct KTabZ { float v[272]; };
constexpr KTabZ make_ktz() {
  KTabZ t{};
  for (int i = 0; i < 272; ++i) t.v[i] = gaussk(i - 31);
  return t;
}
__device__ __constant__ KTabZ KTZ = make_ktz();

// hpass table: tap for (j, e, r) = gaussk(4j + e - r) = KTE.v[4j + e - r + 8],
// idx in [1, 215]. Zero-padded.
struct KTabE { float v[216]; };
constexpr KTabE make_kte() {
  KTabE t{};
  for (int i = 0; i < 216; ++i) t.v[i] = gaussk(i - 8);
  return t;
}
__device__ __constant__ KTabE KTE = make_kte();

// ---------------- pass 1: vertical conv along H ----------------
// 1D grid of 2176 blocks decoded so frame t lands on XCD t%8 (2.09MB frame
// fits one XCD's 4MiB L2; all 34 blocks of a frame share halos there).
// Thread owns 2 columns x 32 rows. Fixed 232-trip input-major loop:
// clamped row address + uniform zero mask for out-of-range rows, so the
// loop unrolls by 8 and tap s_loads amortize over 512 FMAs.
__global__ __launch_bounds__(256, 4) void vpass(const float* __restrict__ x,
                                                float* __restrict__ y) {
  const int lid = blockIdx.x;          // 0..2175
  const int xcd = lid & 7;
  const int s   = lid >> 3;            // 0..271
  const int f   = s / 34;              // 0..7
  const int r34 = s - 34 * f;          // 0..33
  const int t   = (f << 3) | xcd;      // frame
  const int wt  = r34 & 1;
  const int hc  = r34 >> 1;            // 0..16
  const int tid = threadIdx.x;
  const int w   = 2 * (wt * 256 + tid);
  const int h0  = hc * RV;
  if (w >= WWD) return;

  const float* xw = x + (size_t)t * (HH * WWD) + w;

  float ax[RV], ay[RV];
#pragma unroll
  for (int r = 0; r < RV; ++r) { ax[r] = 0.f; ay[r] = 0.f; }

#pragma unroll 8
  for (int bb = 0; bb < 232; ++bb) {           // b = bb - 100
    const int h  = h0 + bb - PADC;
    const int hcl = (h < 0) ? 0 : ((h > HH - 1) ? HH - 1 : h);
    const float m = (h == hcl) ? 1.0f : 0.0f;  // uniform row-valid mask
    float2 v = *(const float2*)(xw + (size_t)hcl * WWD);
    v.x *= m; v.y *= m;
    const float* kb = &KTZ.v[bb + 31];
#pragma unroll
    for (int r = 0; r < RV; ++r) {
      const float kk = kb[-r];                 // wave-uniform scalar
      ax[r] = fmaf(kk, v.x, ax[r]);
      ay[r] = fmaf(kk, v.y, ay[r]);
    }
  }

  float* yp = y + (size_t)t * (HH * WWD) + (size_t)h0 * WWD + w;
#pragma unroll
  for (int r = 0; r < RV; ++r) {
    float2 o; o.x = ax[r]; o.y = ay[r];
    *(float2*)(yp + (size_t)r * WWD) = o;
  }
}

// ---------------- pass 2: horizontal conv along W, in-place ----------------
// Block = 256 threads = 2 rows; lt in [0,120) owns 8 consecutive w of one row.
// Row staged in LDS as 290 float4 blocks (25 zero | 240 data | 25 zero), XOR
// swizzled (q ^ (q>>3)&1) so the stride-2-block sliding reads spread over all
// 8 bank-quads (2-way max = free). 52 ds_read_b128 + 1664 FMA per thread.
__device__ __forceinline__ int swz(int q) { return q ^ ((q >> 3) & 1); }

__global__ __launch_bounds__(256, 4) void hpass(float* __restrict__ y) {
  __shared__ __align__(16) float4 row[2][292];
  const int tid = threadIdx.x;
  const int hh  = tid >> 7;
  const int lt  = tid & 127;
  float* yp = y + (size_t)(blockIdx.x * 2 + hh) * WWD;

  const float4 z4 = {0.f, 0.f, 0.f, 0.f};
  if (lt < 25) {
    row[hh][swz(lt)] = z4;                      // left pad blocks [0,25)
  } else if (lt >= 32 && lt < 57) {
    row[hh][swz(265 + lt - 32)] = z4;           // right pad blocks [265,290)
  }
  if (lt < 120) {
    const int q0 = 25 + 2 * lt;                 // data blocks [25,265)
    row[hh][swz(q0)]     = *(const float4*)(yp + 8 * lt);
    row[hh][swz(q0 + 1)] = *(const float4*)(yp + 8 * lt + 4);
  }
  __syncthreads();

  if (lt < 120) {
    float a0=0.f,a1=0.f,a2=0.f,a3=0.f,a4=0.f,a5=0.f,a6=0.f,a7=0.f;
#pragma unroll 4
    for (int j = 0; j < 52; ++j) {
      const float4 v = row[hh][swz(2 * lt + j)];
      const float* kb = &KTE.v[4 * j + 8];
      {
        const float xv = v.x;
        a0 = fmaf(kb[0], xv, a0);  a1 = fmaf(kb[-1], xv, a1);
        a2 = fmaf(kb[-2], xv, a2); a3 = fmaf(kb[-3], xv, a3);
        a4 = fmaf(kb[-4], xv, a4); a5 = fmaf(kb[-5], xv, a5);
        a6 = fmaf(kb[-6], xv, a6); a7 = fmaf(kb[-7], xv, a7);
      }
      {
        const float xv = v.y;
        a0 = fmaf(kb[1], xv, a0);  a1 = fmaf(kb[0], xv, a1);
        a2 = fmaf(kb[-1], xv, a2); a3 = fmaf(kb[-2], xv, a3);
        a4 = fmaf(kb[-3], xv, a4); a5 = fmaf(kb[-4], xv, a5);
        a6 = fmaf(kb[-5], xv, a6); a7 = fmaf(kb[-6], xv, a7);
      }
      {
        const float xv = v.z;
        a0 = fmaf(kb[2], xv, a0);  a1 = fmaf(kb[1], xv, a1);
        a2 = fmaf(kb[0], xv, a2);  a3 = fmaf(kb[-1], xv, a3);
        a4 = fmaf(kb[-2], xv, a4); a5 = fmaf(kb[-3], xv, a5);
        a6 = fmaf(kb[-4], xv, a6); a7 = fmaf(kb[-5], xv, a7);
      }
      {
        const float xv = v.w;
        a0 = fmaf(kb[3], xv, a0);  a1 = fmaf(kb[2], xv, a1);
        a2 = fmaf(kb[1], xv, a2);  a3 = fmaf(kb[0], xv, a3);
        a4 = fmaf(kb[-1], xv, a4); a5 = fmaf(kb[-2], xv, a5);
        a6 = fmaf(kb[-3], xv, a6); a7 = fmaf(kb[-4], xv, a7);
      }
    }
    float4 o0; o0.x = a0; o0.y = a1; o0.z = a2; o0.w = a3;
    float4 o1; o1.x = a4; o1.y = a5; o1.z = a6; o1.w = a7;
    *(float4*)(yp + 8 * lt)     = o0;
    *(float4*)(yp + 8 * lt + 4) = o1;
  }
}

extern "C" void kernel_launch(void* const* d_in, const int* in_sizes, int n_in,
                              void* d_out, int out_size, void* d_ws, size_t ws_size,
                              hipStream_t stream) {
  const float* x = (const float*)d_in[0];
  float* out = (float*)d_out;
  (void)d_ws; (void)ws_size; (void)in_sizes; (void)n_in; (void)out_size;

  vpass<<<dim3(2 * (HH / RV) * 64), dim3(256), 0, stream>>>(x, out);
  hpass<<<dim3(64 * HH / 2), dim3(256), 0, stream>>>(out);
}